// Round 1
// baseline (465.976 us; speedup 1.0000x reference)
//
#include <hip/hip_runtime.h>
#include <hip/hip_bf16.h>
#include <stdint.h>

#define NN 16384
#define DD 512
#define MARGINV 2.0f
#define EPSV 1e-6f

#define BJ 16
#define JGROUPS 4
#define JRANGE (NN / JGROUPS)   // 4096
#define NTILES (JRANGE / BJ)    // 256
#define ROWB 1040               // 1024 B row + 16 B pad (breaks 32-bank stride alias)
#define BUFB (BJ * ROWB)

typedef __attribute__((ext_vector_type(4))) float          f32x4;
typedef __attribute__((ext_vector_type(8))) short          bf16x8;
typedef __attribute__((ext_vector_type(8))) unsigned short u16x8;

__device__ inline unsigned short f2bf(float f) {
  unsigned int u = __builtin_bit_cast(unsigned int, f);
  u += 0x7FFFu + ((u >> 16) & 1u);   // round-nearest-even
  return (unsigned short)(u >> 16);
}

// ---------------- Kernel 1: row squared norms (fp32) + bf16 copy ----------------
extern "C" __global__ __launch_bounds__(256)
void prep_kernel(const float* __restrict__ x, unsigned short* __restrict__ xb,
                 float* __restrict__ sq) {
  int row  = blockIdx.x * 4 + (threadIdx.x >> 6);
  int lane = threadIdx.x & 63;
  const float* xr = x + (size_t)row * DD + lane * 8;
  f32x4 a = *(const f32x4*)xr;
  f32x4 b = *(const f32x4*)(xr + 4);
  float s = a[0]*a[0]+a[1]*a[1]+a[2]*a[2]+a[3]*a[3]
          + b[0]*b[0]+b[1]*b[1]+b[2]*b[2]+b[3]*b[3];
  #pragma unroll
  for (int off = 1; off < 64; off <<= 1) s += __shfl_xor(s, off, 64);
  u16x8 o;
  o[0]=f2bf(a[0]); o[1]=f2bf(a[1]); o[2]=f2bf(a[2]); o[3]=f2bf(a[3]);
  o[4]=f2bf(b[0]); o[5]=f2bf(b[1]); o[6]=f2bf(b[2]); o[7]=f2bf(b[3]);
  *(u16x8*)(xb + (size_t)row * DD + lane * 8) = o;
  if (lane == 0) sq[row] = s;
}

// ---------------- Kernel 2: fused GEMM (X·X^T) + per-row top-3 ----------------
// block = 256 thr (4 waves); block covers 64 i-rows x one j-group of 4096.
// Per wave: 16 i-rows; A (16x512 bf16) register-resident (64 VGPR).
// B staged 16 j-rows/tile into LDS (double-buffered) via global_load_lds w=16.
// MFMA 16x16x32 bf16; C layout col=lane&15 (j), row=quad*4+reg (i).
extern "C" __global__ __launch_bounds__(256)
void knn_kernel(const unsigned short* __restrict__ xb, const float* __restrict__ sq,
                float* __restrict__ pv, int* __restrict__ pi) {
  __shared__ __align__(16) char lds[2 * BUFB];  // 33,280 B
  const int tid  = threadIdx.x;
  const int wave = tid >> 6;
  const int lane = tid & 63;
  const int quad = lane >> 4;
  const int r16  = lane & 15;
  const int bi   = blockIdx.x >> 2;
  const int bj   = blockIdx.x & 3;
  const int ibase  = bi * 64 + wave * 16;
  const int jbase0 = bj * JRANGE;

  // A fragments: A[m=lane&15][k=quad*8+t], full K=512 -> 16 chunks
  bf16x8 afrag[16];
  {
    const unsigned short* arow = xb + (size_t)(ibase + r16) * DD + quad * 8;
    #pragma unroll
    for (int kc = 0; kc < 16; ++kc)
      afrag[kc] = *(const bf16x8*)(arow + kc * 32);
  }

  float t0v[4], t1v[4], t2v[4];
  int   t0i[4], t1i[4], t2i[4];
  #pragma unroll
  for (int r = 0; r < 4; ++r) {
    t0v[r] = t1v[r] = t2v[r] = 3.0e38f;
    t0i[r] = t1i[r] = t2i[r] = 0x7FFFFFFF;
  }

  auto stage = [&](int jt, int buf) {
    const int jrow0 = jbase0 + jt * BJ;
    #pragma unroll
    for (int q = 0; q < 4; ++q) {
      const int rr = wave + q * 4;                       // wave-uniform row id
      const unsigned short* gsrc = xb + (size_t)(jrow0 + rr) * DD + lane * 8;
      char* ldst = lds + buf * BUFB + rr * ROWB;         // wave-uniform LDS base
      __builtin_amdgcn_global_load_lds((__attribute__((address_space(1))) void*)gsrc,
                                       (__attribute__((address_space(3))) void*)ldst,
                                       16, 0, 0);
    }
  };

  stage(0, 0);
  for (int jt = 0; jt < NTILES; ++jt) {
    __syncthreads();                                     // staged jt ready; jt-1 compute done
    if (jt + 1 < NTILES) stage(jt + 1, (jt + 1) & 1);
    const char* brow = lds + (jt & 1) * BUFB + r16 * ROWB + quad * 16;
    f32x4 acc = {0.f, 0.f, 0.f, 0.f};
    #pragma unroll
    for (int kc = 0; kc < 16; ++kc) {
      bf16x8 bfrag = *(const bf16x8*)(brow + kc * 64);
      acc = __builtin_amdgcn_mfma_f32_16x16x32_bf16(afrag[kc], bfrag, acc, 0, 0, 0);
    }
    const int j   = jbase0 + jt * BJ + r16;              // this lane's column
    const float sqj = sq[j];
    #pragma unroll
    for (int r = 0; r < 4; ++r) {
      float val = fmaf(-2.0f, acc[r], sqj);              // sq[j] - 2*dot
      if (val < t2v[r]) {                                // early-out (rare path)
        bool lt0 = val < t0v[r];
        bool lt1 = val < t1v[r];
        t2v[r] = lt1 ? t1v[r] : val;  t2i[r] = lt1 ? t1i[r] : j;
        t1v[r] = lt0 ? t0v[r] : (lt1 ? val : t1v[r]);
        t1i[r] = lt0 ? t0i[r] : (lt1 ? j   : t1i[r]);
        t0v[r] = lt0 ? val : t0v[r];  t0i[r] = lt0 ? j : t0i[r];
      }
    }
  }

  // ------- block-level merge: 16 lanes (r16) per i -> one top-3 per (i, bj) -------
  __syncthreads();
  float* mv = (float*)lds;
  int*   mi = (int*)(lds + 64 * 48 * 4);                 // 12,288 B each, fits 33 KB
  #pragma unroll
  for (int r = 0; r < 4; ++r) {
    int il   = wave * 16 + quad * 4 + r;
    int base = il * 48 + r16 * 3;
    mv[base+0] = t0v[r]; mv[base+1] = t1v[r]; mv[base+2] = t2v[r];
    mi[base+0] = t0i[r]; mi[base+1] = t1i[r]; mi[base+2] = t2i[r];
  }
  __syncthreads();
  if (tid < 64) {
    float b0 = 3.0e38f, b1 = 3.0e38f, b2 = 3.0e38f;
    int   x0 = 0x7FFFFFFF, x1 = 0x7FFFFFFF, x2 = 0x7FFFFFFF;
    for (int s = 0; s < 48; ++s) {
      float v  = mv[tid * 48 + s];
      int   ix = mi[tid * 48 + s];
      bool l2 = (v < b2) || (v == b2 && ix < x2);         // (val,idx) lexicographic
      if (l2) {
        bool l0 = (v < b0) || (v == b0 && ix < x0);
        bool l1 = (v < b1) || (v == b1 && ix < x1);
        b2 = l1 ? b1 : v;               x2 = l1 ? x1 : ix;
        b1 = l0 ? b0 : (l1 ? v : b1);   x1 = l0 ? x0 : (l1 ? ix : x1);
        b0 = l0 ? v : b0;               x0 = l0 ? ix : x0;
      }
    }
    int gi = bi * 64 + tid;
    int ob = (gi * JGROUPS + bj) * 3;
    pv[ob+0] = b0; pv[ob+1] = b1; pv[ob+2] = b2;
    pi[ob+0] = x0; pi[ob+1] = x1; pi[ob+2] = x2;
  }
}

// ---------------- Kernel 3: merge partials, fp32 norms, hinge, mean ----------------
extern "C" __global__ __launch_bounds__(256)
void finalize_kernel(const float* __restrict__ x, const float* __restrict__ pos,
                     const float* __restrict__ pv, const int* __restrict__ pi,
                     float* __restrict__ out) {
  __shared__ float wsum[4];
  int i    = blockIdx.x * 4 + (threadIdx.x >> 6);
  int wave = threadIdx.x >> 6;
  int lane = threadIdx.x & 63;
  int neg = 0;
  if (lane == 0) {
    float b0 = 3.0e38f, b1 = 3.0e38f, b2 = 3.0e38f;
    int   x0 = 0x7FFFFFFF, x1 = 0x7FFFFFFF, x2 = 0x7FFFFFFF;
    #pragma unroll
    for (int s = 0; s < JGROUPS * 3; ++s) {
      float v  = pv[i * (JGROUPS * 3) + s];
      int   ix = pi[i * (JGROUPS * 3) + s];
      bool l2 = (v < b2) || (v == b2 && ix < x2);
      if (l2) {
        bool l0 = (v < b0) || (v == b0 && ix < x0);
        bool l1 = (v < b1) || (v == b1 && ix < x1);
        b2 = l1 ? b1 : v;               x2 = l1 ? x1 : ix;
        b1 = l0 ? b0 : (l1 ? v : b1);   x1 = l0 ? x0 : (l1 ? ix : x1);
        b0 = l0 ? v : b0;               x0 = l0 ? ix : x0;
      }
    }
    neg = x2;   // 3rd-smallest distance (self is rank 0) -> 2nd NN
  }
  neg = __shfl(neg, 0, 64);
  const float* xr = x   + (size_t)i * DD + lane * 8;
  const float* pr = pos + (size_t)i * DD + lane * 8;
  const float* nr = x   + (size_t)neg * DD + lane * 8;
  f32x4 xa = *(const f32x4*)xr, xb4 = *(const f32x4*)(xr + 4);
  f32x4 pa = *(const f32x4*)pr, pb  = *(const f32x4*)(pr + 4);
  f32x4 na = *(const f32x4*)nr, nb  = *(const f32x4*)(nr + 4);
  float sap = 0.f, san = 0.f;
  #pragma unroll
  for (int k = 0; k < 4; ++k) {
    float d0 = xa[k]  - pa[k] + EPSV; sap = fmaf(d0, d0, sap);
    float d1 = xa[k]  - na[k] + EPSV; san = fmaf(d1, d1, san);
    float d2 = xb4[k] - pb[k] + EPSV; sap = fmaf(d2, d2, sap);
    float d3 = xb4[k] - nb[k] + EPSV; san = fmaf(d3, d3, san);
  }
  #pragma unroll
  for (int off = 1; off < 64; off <<= 1) {
    sap += __shfl_xor(sap, off, 64);
    san += __shfl_xor(san, off, 64);
  }
  if (lane == 0) {
    float l = sqrtf(sap) - sqrtf(san) + MARGINV;
    wsum[wave] = l > 0.f ? l : 0.f;
  }
  __syncthreads();
  if (threadIdx.x == 0) {
    atomicAdd(out, (wsum[0] + wsum[1] + wsum[2] + wsum[3]) * (1.0f / NN));
  }
}

// ---------------- host ----------------
extern "C" void kernel_launch(void* const* d_in, const int* in_sizes, int n_in,
                              void* d_out, int out_size, void* d_ws, size_t ws_size,
                              hipStream_t stream) {
  const float* x   = (const float*)d_in[0];
  const float* pos = (const float*)d_in[1];
  char* ws = (char*)d_ws;
  unsigned short* xb = (unsigned short*)ws;                              // 16 MB
  float* sq = (float*)(ws + (size_t)NN * DD * 2);                        // 64 KB
  float* pv = (float*)(ws + (size_t)NN * DD * 2 + (size_t)NN * 4);       // 768 KB
  int*   pi = (int*)  (ws + (size_t)NN * DD * 2 + (size_t)NN * 4
                          + (size_t)NN * JGROUPS * 3 * 4);               // 768 KB

  hipMemsetAsync(d_out, 0, sizeof(float), stream);
  prep_kernel<<<NN / 4, 256, 0, stream>>>(x, xb, sq);
  knn_kernel<<<(NN / 64) * JGROUPS, 256, 0, stream>>>(xb, sq, pv, pi);
  finalize_kernel<<<NN / 4, 256, 0, stream>>>(x, pos, pv, pi, (float*)d_out);
}